// Round 5
// baseline (828.750 us; speedup 1.0000x reference)
//
#include <hip/hip_runtime.h>

#define HD 128

typedef __attribute__((ext_vector_type(8))) short bf16x8;
typedef __attribute__((ext_vector_type(4))) float f32x4;
typedef __attribute__((ext_vector_type(4))) unsigned int u32x4;

static __device__ __forceinline__ float bf2f(unsigned short u) {
    union { unsigned int i; float f; } c; c.i = ((unsigned int)u) << 16; return c.f;
}
static __device__ __forceinline__ unsigned short f2bf(float f) {
    union { float f; unsigned int i; } c; c.f = f;
    unsigned int lsb = (c.i >> 16) & 1;
    c.i += 0x7fffu + lsb;
    return (unsigned short)(c.i >> 16);
}

// ---------------- spline second-derivative solve (natural cubic, K=5) ----------
__global__ void spline_solve(const float* __restrict__ knots,
                             const float* __restrict__ vals,
                             float* __restrict__ M) {
    int f = threadIdx.x;  // 128 features
    float kn[5], v[5];
#pragma unroll
    for (int i = 0; i < 5; ++i) { kn[i] = knots[i]; v[i] = vals[f * 5 + i]; }
    float h[4], sl[4];
#pragma unroll
    for (int i = 0; i < 4; ++i) { h[i] = kn[i + 1] - kn[i]; sl[i] = (v[i + 1] - v[i]) / h[i]; }
    float r0 = 6.f * (sl[1] - sl[0]);
    float r1 = 6.f * (sl[2] - sl[1]);
    float r2 = 6.f * (sl[3] - sl[2]);
    float d0 = 2.f * (h[0] + h[1]), d1 = 2.f * (h[1] + h[2]), d2 = 2.f * (h[2] + h[3]);
    float e0 = h[1], e1 = h[2];
    float w1 = e0 / d0;  float d1p = d1 - w1 * e0;  float r1p = r1 - w1 * r0;
    float w2 = e1 / d1p; float d2p = d2 - w2 * e1;  float r2p = r2 - w2 * r1p;
    float x2 = r2p / d2p;
    float x1 = (r1p - e1 * x2) / d1p;
    float x0 = (r0 - e0 * x1) / d0;
    M[f * 5 + 0] = 0.f; M[f * 5 + 1] = x0; M[f * 5 + 2] = x1; M[f * 5 + 3] = x2; M[f * 5 + 4] = 0.f;
}

// ---------------- x -> bf16 cast ----------------------------------------------
__global__ void xcast(const float* __restrict__ x, unsigned short* __restrict__ xb) {
    long i = ((long)blockIdx.x * blockDim.x + threadIdx.x) * 8;
    float4 f0 = *(const float4*)(x + i);
    float4 f1 = *(const float4*)(x + i + 4);
    ushort4 o0, o1;
    o0.x = f2bf(f0.x); o0.y = f2bf(f0.y); o0.z = f2bf(f0.z); o0.w = f2bf(f0.w);
    o1.x = f2bf(f1.x); o1.y = f2bf(f1.y); o1.z = f2bf(f1.z); o1.w = f2bf(f1.w);
    *(ushort4*)(xb + i) = o0;
    *(ushort4*)(xb + i + 4) = o1;
}

// ---------------- weight prep: U_r = W_r @ L^T (mats 0..5), kan cast (mat 6) ---
// Output layout Wt[mat][c][k] (k-contiguous per out col): GEMM uses B[k][c]=Wt[c][k].
__global__ void uprep(const float* __restrict__ W1, const float* __restrict__ W2,
                      const float* __restrict__ l1, const float* __restrict__ l2,
                      const float* __restrict__ kw, unsigned short* __restrict__ Wt) {
    int mat = blockIdx.y, c = blockIdx.x, k = threadIdx.x;
    if (mat == 6) {
        Wt[(long)6 * 16384 + c * HD + k] = f2bf(kw[c * HD + k]);
        return;
    }
    const float* Wr = (mat < 3) ? (W1 + (long)mat * 16384) : (W2 + (long)(mat - 3) * 16384);
    const float* L  = (mat < 3) ? l1 : l2;
    __shared__ float Lrow[HD];
    Lrow[k] = L[c * HD + k];
    __syncthreads();
    float s = 0.f;
#pragma unroll 8
    for (int j = 0; j < HD; ++j) s += Wr[k * HD + j] * Lrow[j];
    Wt[(long)mat * 16384 + c * HD + k] = f2bf(s);
}

// ---------------- MFMA GEMM -----------------------------------------------------
// MODE 1: C(n x 128, bf16) = relu( Ag(n x 384, bf16) @ [U0;U1;U2] + bias )
// MODE 2: KAN: kanlin = h(n x 128, bf16) @ kanW + kan_b; affine; spline; dot fc_w
template <int MODE>
__global__ __launch_bounds__(256) void mfma_gemm(
    const unsigned short* __restrict__ A, const unsigned short* __restrict__ Wt,
    void* __restrict__ Out, const float* __restrict__ bias,
    const float* __restrict__ alpha, const float* __restrict__ beta,
    const float* __restrict__ knots, const float* __restrict__ vals,
    const float* __restrict__ Msp, const float* __restrict__ fcw,
    const float* __restrict__ fcb, int n) {
    constexpr int NREL = (MODE == 1) ? 3 : 1;
    constexpr int RS   = (MODE == 1) ? 384 : 128;
    __shared__ unsigned short As[64 * HD];   // 16 KB, XOR-swizzled
    __shared__ unsigned short Ws[HD * HD];   // 32 KB, XOR-swizzled
    const int t = threadIdx.x;
    const int row0 = blockIdx.x * 64;
    const int w = t >> 6;
    const int lane = t & 63;
    const int m = lane & 15;
    const int g = lane >> 4;
    const int sw = (m & 7) << 4;

    f32x4 acc[8];
#pragma unroll
    for (int ct = 0; ct < 8; ++ct) acc[ct] = (f32x4){0.f, 0.f, 0.f, 0.f};

#pragma unroll
    for (int rel = 0; rel < NREL; ++rel) {
        if (rel) __syncthreads();
        const unsigned short* Wg = Wt + (long)rel * 16384;
        for (int i = t; i < 2048; i += 256) {
            u32x4 v = *(const u32x4*)(Wg + i * 8);
            int byte = (i * 16) ^ (((i >> 4) & 7) << 4);
            *(u32x4*)((char*)Ws + byte) = v;
        }
        for (int i = t; i < 1024; i += 256) {
            int rr = i >> 4;
            int k8 = (i & 15) << 3;
            int row = row0 + rr;
            u32x4 v = (u32x4){0u, 0u, 0u, 0u};
            if (row < n) v = *(const u32x4*)(A + (long)row * RS + rel * HD + k8);
            int byte = (i * 16) ^ ((rr & 7) << 4);
            *(u32x4*)((char*)As + byte) = v;
        }
        __syncthreads();
#pragma unroll
        for (int ks = 0; ks < 4; ++ks) {
            const int kb = ks * 64 + g * 16;
            bf16x8 af = *(const bf16x8*)((const char*)As + ((((w * 16 + m) << 8) + kb) ^ sw));
#pragma unroll
            for (int ct = 0; ct < 8; ++ct) {
                bf16x8 bf = *(const bf16x8*)((const char*)Ws + ((((ct * 16 + m) << 8) + kb) ^ sw));
                acc[ct] = __builtin_amdgcn_mfma_f32_16x16x32_bf16(af, bf, acc[ct], 0, 0, 0);
            }
        }
    }

    if (MODE == 1) {
        unsigned short* C = (unsigned short*)Out;
#pragma unroll
        for (int ct = 0; ct < 8; ++ct) {
            float bv = bias[ct * 16 + m];
#pragma unroll
            for (int r = 0; r < 4; ++r) {
                int row = row0 + w * 16 + g * 4 + r;
                if (row < n)
                    C[(long)row * HD + ct * 16 + m] = f2bf(fmaxf(acc[ct][r] + bv, 0.f));
            }
        }
    } else {
        float kn[5];
#pragma unroll
        for (int i = 0; i < 5; ++i) kn[i] = knots[i];
        float part[4] = {0.f, 0.f, 0.f, 0.f};
#pragma unroll
        for (int ct = 0; ct < 8; ++ct) {
            int f = ct * 16 + m;
            float kb = bias[f], al = alpha[f], be = beta[f], fw = fcw[f];
#pragma unroll
            for (int r = 0; r < 4; ++r) {
                float xv = al * (acc[ct][r] + kb) + be;
                int j = -1;
#pragma unroll
                for (int k = 0; k < 5; ++k) j += (xv >= kn[k]) ? 1 : 0;
                j = max(0, min(3, j));
                float t0 = kn[j], t1 = kn[j + 1];
                float hj = t1 - t0;
                float y0 = vals[f * 5 + j], y1 = vals[f * 5 + j + 1];
                float M0 = Msp[f * 5 + j], M1 = Msp[f * 5 + j + 1];
                float a = t1 - xv, b = xv - t0;
                float inv6h = 1.f / (6.f * hj);
                float s = M0 * a * a * a * inv6h + M1 * b * b * b * inv6h
                        + (y0 / hj - M0 * hj / 6.f) * a + (y1 / hj - M1 * hj / 6.f) * b;
                part[r] += s * fw;
            }
        }
#pragma unroll
        for (int o = 1; o < 16; o <<= 1) {
#pragma unroll
            for (int r = 0; r < 4; ++r) part[r] += __shfl_xor(part[r], o);
        }
        if (m == 0) {
#pragma unroll
            for (int r = 0; r < 4; ++r) {
                int row = row0 + w * 16 + g * 4 + r;
                if (row < n) ((float*)Out)[row] = part[r] + fcb[0];
            }
        }
    }
}

// ---------------- CSR build -----------------------------------------------------
__global__ void csr_count3(const int* __restrict__ e0, const int* __restrict__ e1,
                           const int* __restrict__ e2, int* __restrict__ counts,
                           int E, int N) {
    int r = blockIdx.y;
    const int* dst = (r == 0) ? e0 : ((r == 1) ? e1 : e2);
    int e = blockIdx.x * blockDim.x + threadIdx.x;
    if (e < E) atomicAdd(&counts[(long)r * N + dst[e]], 1);
}

__global__ __launch_bounds__(256) void scanA(const int* __restrict__ cnt,
                                             int* __restrict__ S,
                                             int* __restrict__ bsum, int n) {
    __shared__ int ts[256];
    const int t = threadIdx.x;
    const int base = blockIdx.x * 2048 + t * 8;
    int v[8];
    int s = 0;
#pragma unroll
    for (int i = 0; i < 8; ++i) {
        int j = base + i;
        v[i] = (j < n) ? cnt[j] : 0;
        s += v[i];
    }
    ts[t] = s;
    __syncthreads();
    for (int off = 1; off < 256; off <<= 1) {
        int x = (t >= off) ? ts[t - off] : 0;
        __syncthreads();
        ts[t] += x;
        __syncthreads();
    }
    int excl = ts[t] - s;
#pragma unroll
    for (int i = 0; i < 8; ++i) {
        int j = base + i;
        if (j < n) S[j] = excl;
        excl += v[i];
    }
    if (t == 255) bsum[blockIdx.x] = ts[255];
}

__global__ __launch_bounds__(256) void scanC(int* __restrict__ S,
                                             const int* __restrict__ bsum,
                                             int n, int total) {
    __shared__ int red[256];
    const int t = threadIdx.x;
    int acc = 0;
    for (int b = t; b < blockIdx.x; b += 256) acc += bsum[b];
    red[t] = acc;
    __syncthreads();
    for (int o = 128; o; o >>= 1) {
        if (t < o) red[t] += red[t + o];
        __syncthreads();
    }
    const int off = red[0];
    const int base = blockIdx.x * 2048 + t * 8;
#pragma unroll
    for (int i = 0; i < 8; ++i) {
        int j = base + i;
        if (j < n) S[j] += off;
    }
    if (blockIdx.x == gridDim.x - 1 && t == 0) S[n] = total;
}

// ---------------- two-phase bucketed fill (bucket = 64 consecutive dsts) -------
__global__ void bcur_init(const int* __restrict__ S, int* __restrict__ bcur,
                          int N, int NB) {
    int i = blockIdx.x * blockDim.x + threadIdx.x;
    if (i < 3 * NB) {
        int r = i / NB, b = i - r * NB;
        bcur[i] = S[(long)r * N + b * 64];
    }
}

__global__ void bucket_fill(const int* __restrict__ e0, const int* __restrict__ e1,
                            const int* __restrict__ e2, int* __restrict__ bcur,
                            unsigned int* __restrict__ P, int E, int NB) {
    int r = blockIdx.y;
    const int* eb = (r == 0) ? e0 : ((r == 1) ? e1 : e2);
    int e = blockIdx.x * blockDim.x + threadIdx.x;
    if (e < E) {
        int dst = eb[e], src = eb[E + e];
        int b = dst >> 6;
        int pos = atomicAdd(&bcur[r * NB + b], 1);
        P[pos] = ((unsigned)(dst & 63) << 16) | (unsigned)src;
    }
}

__global__ __launch_bounds__(256) void bucket_scatter(const unsigned int* __restrict__ P,
                                                      const int* __restrict__ S,
                                                      unsigned short* __restrict__ srcs,
                                                      int N, int NB) {
    __shared__ int cur[64];
    const int b = blockIdx.x, r = blockIdx.y;
    const int d0 = b * 64;
    const int t = threadIdx.x;
    if (t < 64) {
        int d = d0 + t;
        cur[t] = (d < N) ? S[(long)r * N + d] : 0;
    }
    __syncthreads();
    const int endIdx = min(d0 + 64, N);
    const int pbeg = S[(long)r * N + d0];
    const int pend = S[(long)r * N + endIdx];
    for (int e = pbeg + t; e < pend; e += 256) {
        unsigned int pk = P[e];
        int pos = atomicAdd(&cur[pk >> 16], 1);
        srcs[pos] = (unsigned short)(pk & 0xFFFFu);
    }
}

// ---------------- fused 3-relation gather agg (bf16 in, bf16 out, 3 planes) ----
__global__ __launch_bounds__(256) void csr_agg3(const unsigned short* __restrict__ X,
                                                const int* __restrict__ S,
                                                const unsigned short* __restrict__ srcs,
                                                unsigned short* __restrict__ Ag, int N) {
    const int g = threadIdx.x >> 5;
    const int lane = threadIdx.x & 31;
    const int d = blockIdx.x * 8 + g;
    if (d >= N) return;
    const unsigned short* Xb = X + lane * 4;
#pragma unroll
    for (int r = 0; r < 3; ++r) {
        const int beg = S[(long)r * N + d];
        const int end = S[(long)r * N + d + 1];
        float a0[4] = {0.f, 0.f, 0.f, 0.f};
        float a1[4] = {0.f, 0.f, 0.f, 0.f};
        float a2[4] = {0.f, 0.f, 0.f, 0.f};
        float a3[4] = {0.f, 0.f, 0.f, 0.f};
        int e = beg;
        for (; e + 3 < end; e += 4) {
            int s0 = srcs[e], s1 = srcs[e + 1], s2 = srcs[e + 2], s3 = srcs[e + 3];
            ushort4 u0 = *(const ushort4*)&Xb[(long)s0 * HD];
            ushort4 u1 = *(const ushort4*)&Xb[(long)s1 * HD];
            ushort4 u2 = *(const ushort4*)&Xb[(long)s2 * HD];
            ushort4 u3 = *(const ushort4*)&Xb[(long)s3 * HD];
            a0[0] += bf2f(u0.x); a0[1] += bf2f(u0.y); a0[2] += bf2f(u0.z); a0[3] += bf2f(u0.w);
            a1[0] += bf2f(u1.x); a1[1] += bf2f(u1.y); a1[2] += bf2f(u1.z); a1[3] += bf2f(u1.w);
            a2[0] += bf2f(u2.x); a2[1] += bf2f(u2.y); a2[2] += bf2f(u2.z); a2[3] += bf2f(u2.w);
            a3[0] += bf2f(u3.x); a3[1] += bf2f(u3.y); a3[2] += bf2f(u3.z); a3[3] += bf2f(u3.w);
        }
        for (; e < end; ++e) {
            ushort4 u0 = *(const ushort4*)&Xb[(long)srcs[e] * HD];
            a0[0] += bf2f(u0.x); a0[1] += bf2f(u0.y); a0[2] += bf2f(u0.z); a0[3] += bf2f(u0.w);
        }
        ushort4 o;
        o.x = f2bf((a0[0] + a1[0]) + (a2[0] + a3[0]));
        o.y = f2bf((a0[1] + a1[1]) + (a2[1] + a3[1]));
        o.z = f2bf((a0[2] + a1[2]) + (a2[2] + a3[2]));
        o.w = f2bf((a0[3] + a1[3]) + (a2[3] + a3[3]));
        *(ushort4*)&Ag[(long)d * 384 + r * HD + lane * 4] = o;
    }
}

extern "C" void kernel_launch(void* const* d_in, const int* in_sizes, int n_in,
                              void* d_out, int out_size, void* d_ws, size_t ws_size,
                              hipStream_t stream) {
    const float* x       = (const float*)d_in[0];
    const int*   eA[3]   = {(const int*)d_in[1], (const int*)d_in[2], (const int*)d_in[3]};
    const float* W1      = (const float*)d_in[4];
    const float* lin1_w  = (const float*)d_in[5];
    const float* lin1_b  = (const float*)d_in[6];
    const float* W2      = (const float*)d_in[7];
    const float* lin2_w  = (const float*)d_in[8];
    const float* lin2_b  = (const float*)d_in[9];
    const float* kan_w   = (const float*)d_in[10];
    const float* kan_b   = (const float*)d_in[11];
    const float* alpha   = (const float*)d_in[12];
    const float* beta    = (const float*)d_in[13];
    const float* knots   = (const float*)d_in[14];
    const float* spline_vals = (const float*)d_in[15];
    const float* fc_w    = (const float*)d_in[16];
    const float* fc_b    = (const float*)d_in[17];

    const int N = in_sizes[0] / HD;
    const int E = in_sizes[1] / 2;
    const int n3 = 3 * N;
    const int NB = (N + 63) / 64;

    // ---- workspace carve (256B-aligned blocks) ----
    char* p = (char*)d_ws;
    auto carve = [&](size_t bytes) {
        char* q = p;
        p += (bytes + 255) & ~(size_t)255;
        return q;
    };
    float* M              = (float*)carve(4096);
    unsigned short* Wt    = (unsigned short*)carve((size_t)9 * 16384 * 2);
    int* counts           = (int*)carve((size_t)n3 * 4);
    int* S                = (int*)carve((size_t)(n3 + 1) * 4);
    int* bsum             = (int*)carve(4096);
    int* bcur             = (int*)carve((size_t)3 * NB * 4);
    unsigned short* srcs  = (unsigned short*)carve((size_t)3 * E * 2);
    unsigned int* P       = (unsigned int*)carve((size_t)3 * E * 4);
    unsigned short* xb    = (unsigned short*)carve((size_t)N * HD * 2);
    unsigned short* hb    = (unsigned short*)carve((size_t)N * HD * 2);
    unsigned short* Ag    = (unsigned short*)carve((size_t)N * 384 * 2);

    const int g64      = (N + 63) / 64;
    const int aggGrid  = (N + 7) / 8;
    const int edgeGrid = (E + 255) / 256;
    const int scanGrid = (n3 + 2047) / 2048;

    // small precomputes
    spline_solve<<<1, 128, 0, stream>>>(knots, spline_vals, M);
    xcast<<<(N * HD) / (256 * 8), 256, 0, stream>>>(x, xb);
    uprep<<<dim3(128, 7), 128, 0, stream>>>(W1, W2, lin1_w, lin2_w, kan_w, Wt);

    // ---- CSR build (once; reused by both layers) ----
    hipMemsetAsync(counts, 0, (size_t)n3 * 4, stream);
    csr_count3<<<dim3(edgeGrid, 3), 256, 0, stream>>>(eA[0], eA[1], eA[2], counts, E, N);
    scanA<<<scanGrid, 256, 0, stream>>>(counts, S, bsum, n3);
    scanC<<<scanGrid, 256, 0, stream>>>(S, bsum, n3, 3 * E);
    bcur_init<<<(3 * NB + 255) / 256, 256, 0, stream>>>(S, bcur, N, NB);
    bucket_fill<<<dim3(edgeGrid, 3), 256, 0, stream>>>(eA[0], eA[1], eA[2], bcur, P, E, NB);
    bucket_scatter<<<dim3(NB, 3), 256, 0, stream>>>(P, S, srcs, N, NB);

    // ---- layer 1: Ag = [A_r x]_cat ; h1 = relu(Ag @ [U1_r] + b1) ----
    csr_agg3<<<aggGrid, 256, 0, stream>>>(xb, S, srcs, Ag, N);
    mfma_gemm<1><<<g64, 256, 0, stream>>>(Ag, Wt, hb, lin1_b, nullptr, nullptr,
                                          nullptr, nullptr, nullptr, nullptr, nullptr, N);

    // ---- layer 2 ----
    csr_agg3<<<aggGrid, 256, 0, stream>>>(hb, S, srcs, Ag, N);
    mfma_gemm<1><<<g64, 256, 0, stream>>>(Ag, Wt + (size_t)3 * 16384, hb, lin2_b, nullptr,
                                          nullptr, nullptr, nullptr, nullptr, nullptr, nullptr, N);

    // ---- KAN linear + spline + fc (fused, MFMA) ----
    mfma_gemm<2><<<g64, 256, 0, stream>>>(hb, Wt + (size_t)6 * 16384, d_out, kan_b, alpha,
                                          beta, knots, spline_vals, M, fc_w, fc_b, N);
}